// Round 8
// baseline (275.131 us; speedup 1.0000x reference)
//
#include <hip/hip_runtime.h>

typedef unsigned long long u64;
typedef unsigned int u32;

#define R_TOT 159882
#define POST 1000
#define IMG_SZ 800.0f
#define NMS_TH 0.7f
#define BBOX_CLIP 4.135166556742356f
#define LCAP 1024

__device__ __forceinline__ float fadd_(float a, float b){ return __fadd_rn(a,b); }
__device__ __forceinline__ float fsub_(float a, float b){ return __fsub_rn(a,b); }
__device__ __forceinline__ float fmul_(float a, float b){ return __fmul_rn(a,b); }

__device__ __forceinline__ int lvl_len(int l){ const int L[5]={120000,30000,7500,1875,507}; return L[l]; }
__device__ __forceinline__ int lvl_off(int l){ const int L[5]={0,120000,150000,157500,159375}; return L[l]; }
__device__ __forceinline__ int lvl_k(int l){ const int L[5]={1000,1000,1000,1000,507}; return L[l]; }

__device__ __forceinline__ u32 mono_(u32 u){ return (u & 0x80000000u) ? ~u : (u | 0x80000000u); }

__device__ __forceinline__ u64 readlane64(u64 v, int i){
  u32 lo = (u32)__builtin_amdgcn_readlane((int)(u32)v, i);
  u32 hi = (u32)__builtin_amdgcn_readlane((int)(u32)(v >> 32), i);
  return ((u64)hi << 32) | (u64)lo;
}

// ---------- 1. per-slice 12-bit histogram (wide: 160 blocks x 256 thr) ----------
__global__ __launch_bounds__(256) void k_hist(const float* __restrict__ obj, int* hist16){
  int g = blockIdx.x, sl = blockIdx.y;
  int img = g/5, lvl = g%5;
  int n = lvl_len(lvl), s0 = lvl_off(lvl);
  __shared__ int lh[4096];
  int tid = threadIdx.x;
  for (int i = tid; i < 4096; i += 256) lh[i] = 0;
  __syncthreads();
  int lo = (int)((long long)n * sl / 16), hiS = (int)((long long)n * (sl+1) / 16);
  const float* p = obj + img*R_TOT + s0;
  #pragma unroll 4
  for (int e = lo + tid; e < hiS; e += 256){
    u32 mu = mono_(__float_as_uint(p[e]));
    atomicAdd(&lh[(~mu) >> 20], 1);
  }
  __syncthreads();
  int* dst = hist16 + (g*16 + sl)*4096;
  for (int i = tid; i < 4096; i += 256) dst[i] = lh[i];
}

// ---------- 2. FUSED select+mask: pick + collect (guard-free 8-deep batching) + tie +
//             sort + decode + compact + IoU bitmask (boxes read from LDS).
//             One block per (img,level). ----------
__global__ __launch_bounds__(1024) void k_sel(const float* __restrict__ obj,
                                              const float4* __restrict__ deltas,
                                              const float4* __restrict__ anchors,
                                              const int* __restrict__ hist16,
                                              float4* boxL, float* scoreL,
                                              u64* okeyN, int* ncnt, u64* LTG2){
  int g = blockIdx.x, img = g/5, lvl = g%5;
  int s0 = lvl_off(lvl), n = lvl_len(lvl), k = lvl_k(lvl);
  const float* p = obj + img*R_TOT + s0;
  __shared__ u64 lmain[1024];
  __shared__ u64 lbuf2[1024];
  __shared__ float4 lbox[1024];
  __shared__ float4 cbox[1024];
  __shared__ u64 lokey[1024];
  __shared__ unsigned char lval[1024];
  __shared__ int wsum[16];
  __shared__ int h16s[16];
  __shared__ int sh_bs, sh_rem, sh_sc, lc, lc2, sh_m;
  __shared__ u64 sh_thr;
  int tid = threadIdx.x, lane = tid & 63, wid = tid >> 6;

  if (tid == 0){ lc = 0; lc2 = 0; sh_sc = 0; }
  lmain[tid] = ~0ull;

  // --- phase A: pick — sum 16 slice-histograms (L2-hot), 4 bins/thread ---
  int h0 = 0, h1 = 0, h2 = 0, h3 = 0;
  {
    const int* hb = hist16 + g*16*4096 + 4*tid;
    #pragma unroll
    for (int sl = 0; sl < 16; sl++){
      int4 a = *(const int4*)(hb + sl*4096);
      h0 += a.x; h1 += a.y; h2 += a.z; h3 += a.w;
    }
  }
  int part = h0 + h1 + h2 + h3;
  int x = part;
  for (int d = 1; d < 64; d <<= 1){ int y = __shfl_up(x, d); if (lane >= d) x += y; }
  if (lane == 63) wsum[wid] = x;
  __syncthreads();
  int add = 0;
  for (int w = 0; w < wid; w++) add += wsum[w];
  int incl = x + add, excl = incl - part;
  if (excl < k && k <= incl){
    int cum = excl;
    if (cum + h0 >= k){ sh_bs = 4*tid;   sh_rem = k - cum; }
    else { cum += h0;
      if (cum + h1 >= k){ sh_bs = 4*tid+1; sh_rem = k - cum; }
      else { cum += h1;
        if (cum + h2 >= k){ sh_bs = 4*tid+2; sh_rem = k - cum; }
        else { cum += h2;    sh_bs = 4*tid+3; sh_rem = k - cum; }
      }
    }
  }
  __syncthreads();
  int bs = sh_bs, rem0 = sh_rem;

  // --- phase B: collect. Main loop is GUARD-FREE (all 8 indices provably < n)
  //     so 8 global_load_dword issue back-to-back; single guarded tail batch. ---
  {
    int full = n >> 13;               // iterations where e0+7168 < full*8192 <= n
    for (int it = 0; it < full; it++){
      int e0 = (it << 13) + tid;
      float v[8];
      #pragma unroll
      for (int q = 0; q < 8; q++) v[q] = p[e0 + (q << 10)];
      #pragma unroll
      for (int q = 0; q < 8; q++){
        int e = e0 + (q << 10);
        u32 mu = mono_(__float_as_uint(v[q]));
        u64 key56 = (((u64)(~mu)) << 24) | (u32)(s0 + e);
        int bin = (int)(key56 >> 44);
        if (bin < bs){ int pos = atomicAdd(&lc, 1); lmain[pos] = key56; }   // nb = k-rem <= 999
        else if (bin == bs){ int pos = atomicAdd(&lc2, 1); if (pos < 1024) lbuf2[pos] = key56; }
      }
    }
    // tail: < 8192 elements, one guarded batch
    int e0 = (full << 13) + tid;
    float v[8];
    #pragma unroll
    for (int q = 0; q < 8; q++){
      int e = e0 + (q << 10);
      v[q] = (e < n) ? p[e] : 0.0f;
    }
    #pragma unroll
    for (int q = 0; q < 8; q++){
      int e = e0 + (q << 10);
      if (e < n){
        u32 mu = mono_(__float_as_uint(v[q]));
        u64 key56 = (((u64)(~mu)) << 24) | (u32)(s0 + e);
        int bin = (int)(key56 >> 44);
        if (bin < bs){ int pos = atomicAdd(&lc, 1); lmain[pos] = key56; }
        else if (bin == bs){ int pos = atomicAdd(&lc2, 1); if (pos < 1024) lbuf2[pos] = key56; }
      }
    }
  }
  __syncthreads();
  int nb = lc, c2 = lc2;

  // --- phase C: tie-resolve ---
  if (c2 <= LCAP){
    for (int e = tid; e < c2; e += 1024){
      u64 kk = lbuf2[e];
      int rk = 0;
      for (int q = 0; q < c2; q++) rk += (lbuf2[q] < kk) ? 1 : 0;
      if (rk < rem0){ int p2 = atomicAdd(&sh_sc, 1); lmain[nb + p2] = kk; }
    }
  } else {
    // fallback: 4-bit radix refine over global (never hit on bench data)
    if (tid == 0) sh_thr = ((u64)bs) << 44;
    __syncthreads();
    for (int shift = 40; shift >= 0; shift -= 4){
      if (tid < 16) h16s[tid] = 0;
      __syncthreads();
      u64 pref = sh_thr;
      u64 himask = ~((1ull << (shift+4)) - 1ull);
      for (int e = tid; e < n; e += 1024){
        u32 mu = mono_(__float_as_uint(p[e]));
        u64 kk = (((u64)(~mu)) << 24) | (u32)(s0 + e);
        if ((kk & himask) == (pref & himask)) atomicAdd(&h16s[(int)((kk >> shift) & 15)], 1);
      }
      __syncthreads();
      if (tid == 0){
        int r2 = sh_rem, cum = 0;
        for (int d = 0; d < 16; d++){
          int hb2 = h16s[d];
          if (cum + hb2 >= r2){ sh_thr = pref | ((u64)d << shift); sh_rem = r2 - cum; break; }
          cum += hb2;
        }
      }
      __syncthreads();
    }
    u64 thr = sh_thr;
    for (int e = tid; e < n; e += 1024){
      u32 mu = mono_(__float_as_uint(p[e]));
      u64 kk = (((u64)(~mu)) << 24) | (u32)(s0 + e);
      if ((int)(kk >> 44) == bs && kk <= thr){ int p2 = atomicAdd(&sh_sc, 1); lmain[nb + p2] = kk; }
    }
  }
  __syncthreads();

  // --- phase D: bitonic sort 1024 ---
  for (int k2 = 2; k2 <= 1024; k2 <<= 1){
    for (int j = k2 >> 1; j > 0; j >>= 1){
      __syncthreads();
      int i = tid, ixj = i ^ j;
      if (ixj > i){
        u64 a = lmain[i], b = lmain[ixj];
        bool up = (i & k2) == 0;
        if ((a > b) == up){ lmain[i] = b; lmain[ixj] = a; }
      }
    }
  }
  __syncthreads();

  // --- phase E: decode + clip + valid + sigmoid + okey ---
  int r = tid, t = g*1024 + r;
  if (r < k){
    int idx = (int)(lmain[r] & 0xFFFFFFu);
    float4 a = anchors[idx];
    float4 d = deltas[img*R_TOT + idx];
    float o = obj[img*R_TOT + idx];
    float wa = fsub_(a.z, a.x), ha = fsub_(a.w, a.y);
    float cxa = fadd_(a.x, fmul_(0.5f, wa)), cya = fadd_(a.y, fmul_(0.5f, ha));
    float dw = fminf(d.z, BBOX_CLIP), dh = fminf(d.w, BBOX_CLIP);
    float cx = fadd_(fmul_(d.x, wa), cxa), cy = fadd_(fmul_(d.y, ha), cya);
    float w  = fmul_(expf(dw), wa),        h  = fmul_(expf(dh), ha);
    float x1 = fsub_(cx, fmul_(0.5f, w)), y1 = fsub_(cy, fmul_(0.5f, h));
    float x2 = fadd_(cx, fmul_(0.5f, w)), y2 = fadd_(cy, fmul_(0.5f, h));
    x1 = fminf(fmaxf(x1, 0.0f), IMG_SZ); y1 = fminf(fmaxf(y1, 0.0f), IMG_SZ);
    x2 = fminf(fmaxf(x2, 0.0f), IMG_SZ); y2 = fminf(fmaxf(y2, 0.0f), IMG_SZ);
    bool valid = (fsub_(x2, x1) >= 1e-3f) && (fsub_(y2, y1) >= 1e-3f);
    float e = expf(-o);
    float sig = __fdiv_rn(1.0f, fadd_(1.0f, e));
    float s = valid ? sig : -1.0f;
    u32 sb = __float_as_uint(s);
    u32 ms = (sb & 0x80000000u) ? ~sb : (sb | 0x80000000u);
    float4 b4 = make_float4(x1, y1, x2, y2);
    boxL[t] = b4;
    scoreL[t] = sig;
    lokey[r] = (((u64)(~ms)) << 32) | (u32)(lvl*1000 + r);
    lbox[r] = b4;
    lval[r] = valid ? 1 : 0;
  } else {
    lval[r] = 0;
  }
  __syncthreads();

  // --- phase F: valid-compaction (wave 0): cbox (+801*lvl, LDS) + okey (global) ---
  if (tid < 64){
    int cnt = 0;
    float off = (float)lvl * 801.0f;
    for (int base = 0; base < k; base += 64){
      int r2 = base + lane;
      bool v = (r2 < k) && lval[r2];
      float4 b = lbox[r2 < k ? r2 : 0];
      u64 mask = __ballot(v);
      int before = __popcll(mask & ((1ull << lane) - 1ull));
      if (v){
        int pos = cnt + before;
        cbox[pos] = make_float4(fadd_(b.x,off), fadd_(b.y,off), fadd_(b.z,off), fadd_(b.w,off));
        okeyN[g*1024 + pos] = lokey[r2];
      }
      cnt += __popcll(mask);
    }
    if (lane == 0){ ncnt[g] = cnt; sh_m = cnt; }
  }
  __syncthreads();

  // --- phase G: IoU bitmask (16 waves over 136 triangle tiles; boxes from LDS) ---
  {
    int m = sh_m;
    for (int item = wid; item < 136; item += 16){
      int tr = 0;
      while ((tr+1)*(tr+2)/2 <= item) tr++;
      int tw = item - tr*(tr+1)/2;
      if (tr*64 >= m) continue;
      int j = tr*64 + lane;
      if (j >= m) continue;
      float4 a = cbox[j];
      float areaA = fmul_(fsub_(a.z,a.x), fsub_(a.w,a.y));
      int imax = m - tw*64; if (imax > 64) imax = 64;
      if (tw == tr){
        u64 bitsF = 0;
        for (int ii = lane+1; ii < imax; ii++){
          float4 b = cbox[tw*64 + ii];
          float ltx = fmaxf(a.x, b.x), lty = fmaxf(a.y, b.y);
          float rbx = fminf(a.z, b.z), rby = fminf(a.w, b.w);
          float wx = fmaxf(fsub_(rbx, ltx), 0.0f), wy = fmaxf(fsub_(rby, lty), 0.0f);
          float inter = fmul_(wx, wy);
          float areaB = fmul_(fsub_(b.z,b.x), fsub_(b.w,b.y));
          float den = fadd_(fsub_(fadd_(areaA, areaB), inter), 1e-9f);
          if (__fdiv_rn(inter, den) > NMS_TH) bitsF |= (1ull << ii);
        }
        LTG2[((size_t)(g*1024 + j))*16 + 15] = bitsF;
      } else {
        u64 bits = 0;
        for (int ii = 0; ii < imax; ii++){
          float4 b = cbox[tw*64 + ii];
          float ltx = fmaxf(a.x, b.x), lty = fmaxf(a.y, b.y);
          float rbx = fminf(a.z, b.z), rby = fminf(a.w, b.w);
          float wx = fmaxf(fsub_(rbx, ltx), 0.0f), wy = fmaxf(fsub_(rby, lty), 0.0f);
          float inter = fmul_(wx, wy);
          float areaB = fmul_(fsub_(b.z,b.x), fsub_(b.w,b.y));
          float den = fadd_(fsub_(fadd_(areaA, areaB), inter), 1e-9f);
          if (__fdiv_rn(inter, den) > NMS_TH) bits |= (1ull << ii);
        }
        LTG2[((size_t)(g*1024 + j))*16 + tw] = bits;
      }
    }
  }
}

struct ChunkBuf {
  ulonglong2 v0, v1, v2, v3, v4, v5, v6, v7;   // 16 u64: words 0..14 + diagF (slot 15)
  u64 ok;
};

__device__ __forceinline__ void issue_chunk(const u64* __restrict__ LT2,
                                            const u64* __restrict__ oK,
                                            int c, int lane, ChunkBuf& b){
  int row = c*64 + lane;
  const ulonglong2* rp = (const ulonglong2*)(LT2 + (size_t)row*16);
  b.v0 = rp[0]; b.v1 = rp[1]; b.v2 = rp[2]; b.v3 = rp[3];
  b.v4 = rp[4]; b.v5 = rp[5]; b.v6 = rp[6]; b.v7 = rp[7];
  b.ok = oK[row];
}

__device__ __forceinline__ void consume_chunk(const ChunkBuf& b, int c, int m, int lane,
                                              u64* KwR, u64* runsL, int& cnt){
  int row = c*64 + lane;
  bool inr = row < m;
  u64 supp = 0;
  #define TERM(q, val) supp |= (((q) < c) ? (val) : 0ull) & KwR[q];
  TERM(0,  b.v0.x) TERM(1,  b.v0.y) TERM(2,  b.v1.x) TERM(3,  b.v1.y)
  TERM(4,  b.v2.x) TERM(5,  b.v2.y) TERM(6,  b.v3.x) TERM(7,  b.v3.y)
  TERM(8,  b.v4.x) TERM(9,  b.v4.y) TERM(10, b.v5.x) TERM(11, b.v5.y)
  TERM(12, b.v6.x) TERM(13, b.v6.y) TERM(14, b.v7.x)
  #undef TERM
  u64 fwd = inr ? b.v7.y : 0;
  u64 live = __ballot(inr && (supp == 0));
  u64 fz = __ballot(fwd != 0);
  u64 kept = 0;
  while (1){
    u64 lf = live & fz;
    if (!lf){ kept |= live; break; }       // remaining live lanes suppress nobody
    int i = __builtin_ctzll(lf);
    u64 bi = 1ull << i;
    u64 below = live & (bi - 1ull);        // live lanes before i: fwd==0, batch-keep
    kept |= below | bi;
    live &= ~(below | bi);
    live &= ~readlane64(fwd, i);
  }
  KwR[c] = kept;                            // uniform; in-wave DS ordering suffices
  bool kp = (kept >> lane) & 1ull;
  int before = __popcll(kept & ((1ull << lane) - 1ull));
  if (kp) runsL[cnt + before] = b.ok;
  cnt += __popcll(kept);
}

// ---------- 3. fused greedy scan + merge (r3-verbatim) ----------
__global__ __launch_bounds__(1024) void k_scanmerge(const u64* __restrict__ LTG2,
                                                    const int* __restrict__ ncnt,
                                                    const u64* __restrict__ okeyN,
                                                    const float4* __restrict__ boxL,
                                                    const float* __restrict__ scoreL,
                                                    float* out){
  int img = blockIdx.x, tid = threadIdx.x, lane = tid & 63, wid = tid >> 6;
  __shared__ u64 runs[5*1024];
  __shared__ u64 Kw[5][16];
  __shared__ int cl[5];
  if (wid < 5){
    int l = wid, g = img*5 + l;
    int m = ncnt[g];
    int nch = (m + 63) >> 6;
    const u64* LT2 = LTG2 + ((size_t)g*1024)*16;
    const u64* oK = okeyN + g*1024;
    u64* KwR = &Kw[l][0];
    u64* runsL = &runs[l*1024];
    int cnt = 0;
    ChunkBuf A, B;
    if (nch > 0){
      issue_chunk(LT2, oK, 0, lane, A);
      int c = 0;
      while (c < nch){
        if (c+1 < nch) issue_chunk(LT2, oK, c+1, lane, B);
        consume_chunk(A, c, m, lane, KwR, runsL, cnt);
        c++;
        if (c >= nch) break;
        if (c+1 < nch) issue_chunk(LT2, oK, c+1, lane, A);
        consume_chunk(B, c, m, lane, KwR, runsL, cnt);
        c++;
      }
    }
    if (lane == 0) cl[l] = cnt;
  } else {
    for (int t = tid - 320; t < POST; t += 704){
      out[img*POST*4 + t*4 + 0] = 0.0f;
      out[img*POST*4 + t*4 + 1] = 0.0f;
      out[img*POST*4 + t*4 + 2] = 0.0f;
      out[img*POST*4 + t*4 + 3] = 0.0f;
      out[2*POST*4 + img*POST + t] = -1.0f;
    }
  }
  __syncthreads();
  for (int idx = tid; idx < 5*1024; idx += 1024){
    int l = idx >> 10, i = idx & 1023;
    if (i < cl[l]){
      u64 key = runs[l*1024 + i];
      int o0 = l+1; if (o0 >= 5) o0 -= 5;
      int o1 = l+2; if (o1 >= 5) o1 -= 5;
      int o2 = l+3; if (o2 >= 5) o2 -= 5;
      int o3 = l+4; if (o3 >= 5) o3 -= 5;
      const u64* r0 = runs + (o0 << 10);
      const u64* r1 = runs + (o1 << 10);
      const u64* r2 = runs + (o2 << 10);
      const u64* r3 = runs + (o3 << 10);
      int lo0 = 0, hi0 = cl[o0];
      int lo1 = 0, hi1 = cl[o1];
      int lo2 = 0, hi2 = cl[o2];
      int lo3 = 0, hi3 = cl[o3];
      #pragma unroll 1
      for (int st = 0; st < 11; st++){
        int m0 = (lo0+hi0)>>1, m1 = (lo1+hi1)>>1, m2 = (lo2+hi2)>>1, m3 = (lo3+hi3)>>1;
        u64 a0 = r0[m0], a1 = r1[m1], a2 = r2[m2], a3 = r3[m3];
        if (lo0 < hi0){ if (a0 < key) lo0 = m0+1; else hi0 = m0; }
        if (lo1 < hi1){ if (a1 < key) lo1 = m1+1; else hi1 = m1; }
        if (lo2 < hi2){ if (a2 < key) lo2 = m2+1; else hi2 = m2; }
        if (lo3 < hi3){ if (a3 < key) lo3 = m3+1; else hi3 = m3; }
      }
      int rank = i + lo0 + lo1 + lo2 + lo3;
      if (rank < POST){
        int pos = (int)(key & 0xFFFFFFFFull);
        int lvl = pos / 1000, r = pos - lvl*1000;
        int gg = img*5 + lvl;
        float4 bo = boxL[gg*1024 + r];
        float sc = scoreL[gg*1024 + r];
        out[img*POST*4 + rank*4 + 0] = bo.x;
        out[img*POST*4 + rank*4 + 1] = bo.y;
        out[img*POST*4 + rank*4 + 2] = bo.z;
        out[img*POST*4 + rank*4 + 3] = bo.w;
        out[2*POST*4 + img*POST + rank] = sc;
      }
    }
  }
}

extern "C" void kernel_launch(void* const* d_in, const int* in_sizes, int n_in,
                              void* d_out, int out_size, void* d_ws, size_t ws_size,
                              hipStream_t stream){
  (void)in_sizes; (void)n_in; (void)out_size; (void)ws_size;
  const float*  obj     = (const float*)d_in[0];
  const float4* deltas  = (const float4*)d_in[1];
  const float4* anchors = (const float4*)d_in[2];
  float* out = (float*)d_out;
  char* ws = (char*)d_ws;
  int* hist16  = (int*)(ws + 0);           // 10*16*4096 int -> 2621440
  float4* boxL = (float4*)(ws + 2621440);  // 10*1024 f4     -> 2785280
  float* scoreL= (float*)(ws + 2785280);   // 10*1024 f32    -> 2826240
  u64* okeyN   = (u64*)(ws + 2826240);     // 10*1024 u64    -> 2908160
  u64* LTG2    = (u64*)(ws + 2908160);     // 10*1024*16 u64 -> 4218880
  int* ncnt    = (int*)(ws + 4218880);     // 10 int

  {
    dim3 gh(10, 16);
    k_hist<<<gh, 256, 0, stream>>>(obj, hist16);
  }
  k_sel<<<10, 1024, 0, stream>>>(obj, deltas, anchors, hist16, boxL, scoreL, okeyN, ncnt, LTG2);
  {
    dim3 gm(2);
    k_scanmerge<<<gm, 1024, 0, stream>>>(LTG2, ncnt, okeyN, boxL, scoreL, out);
  }
}

// Round 9
// 169.805 us; speedup vs baseline: 1.6203x; 1.6203x over previous
//
#include <hip/hip_runtime.h>

typedef unsigned long long u64;
typedef unsigned int u32;

#define R_TOT 159882
#define POST 1000
#define IMG_SZ 800.0f
#define NMS_TH 0.7f
#define BBOX_CLIP 4.135166556742356f
#define LCAP 1024
#define MAGIC 0xA5C83D91u

__device__ __forceinline__ float fadd_(float a, float b){ return __fadd_rn(a,b); }
__device__ __forceinline__ float fsub_(float a, float b){ return __fsub_rn(a,b); }
__device__ __forceinline__ float fmul_(float a, float b){ return __fmul_rn(a,b); }

__device__ __forceinline__ int lvl_len(int l){ const int L[5]={120000,30000,7500,1875,507}; return L[l]; }
__device__ __forceinline__ int lvl_off(int l){ const int L[5]={0,120000,150000,157500,159375}; return L[l]; }
__device__ __forceinline__ int lvl_k(int l){ const int L[5]={1000,1000,1000,1000,507}; return L[l]; }

__device__ __forceinline__ u32 mono_(u32 u){ return (u & 0x80000000u) ? ~u : (u | 0x80000000u); }

__device__ __forceinline__ u64 readlane64(u64 v, int i){
  u32 lo = (u32)__builtin_amdgcn_readlane((int)(u32)v, i);
  u32 hi = (u32)__builtin_amdgcn_readlane((int)(u32)(v >> 32), i);
  return ((u64)hi << 32) | (u64)lo;
}

// ---------- 1. FUSED hist+pick+collect: 160 co-resident blocks (512 thr), soft barrier.
//    All cross-block traffic via device atomics (coherent across XCD L2s).
//    Markers use MAGIC (no zero-init needed); histsum/cntg zeroed by sl==0 block
//    behind the Zmark stage. Deadlock-free: 160 blocks x 512thr x 16KB LDS all resident. ----------
__global__ __launch_bounds__(512) void k_histcollect(const float* __restrict__ obj,
                                                     int* histsum, u32* Zmark, u32* Dmark,
                                                     int* bstarG, int* remG,
                                                     int* cntg, int* cnt2,
                                                     u64* mainG, u64* LbufG){
  int g = blockIdx.x, sl = blockIdx.y;
  int img = g/5, lvl = g%5;
  int n = lvl_len(lvl), s0 = lvl_off(lvl), k = lvl_k(lvl);
  int tid = threadIdx.x, lane = tid & 63, wid = tid >> 6;
  __shared__ __align__(16) char arena[16384];   // lh[4096] then lmain[1024]+lbuf2[1024]
  __shared__ int wsum[8];
  __shared__ int sh_bs, sh_rem, lc, lc2, gbase, gbase2;
  int* lh = (int*)arena;

  // --- build slice histogram in LDS ---
  for (int i = tid; i < 4096; i += 512) lh[i] = 0;
  __syncthreads();
  int lo = (int)((long long)n * sl / 16), hiS = (int)((long long)n * (sl+1) / 16);
  const float* p = obj + img*R_TOT + s0;
  #pragma unroll 4
  for (int e = lo + tid; e < hiS; e += 512){
    u32 mu = mono_(__float_as_uint(p[e]));
    atomicAdd(&lh[(~mu) >> 20], 1);
  }
  __syncthreads();

  // --- stage 0 (sl==0): zero histsum + counters, then publish Zmark ---
  if (sl == 0){
    for (int i = tid; i < 4096; i += 512) atomicExch((u32*)&histsum[g*4096 + i], 0u);
    if (tid == 0) atomicExch((u32*)&cntg[g], 0u);
    if (tid == 1) atomicExch((u32*)&cnt2[g], 0u);
    __threadfence();
    __syncthreads();
    if (tid == 0) atomicExch(&Zmark[g], MAGIC);
  }
  // --- stage 1: wait for zero-done ---
  if (tid == 0){
    while (atomicAdd(&Zmark[g], 0u) != MAGIC) __builtin_amdgcn_s_sleep(16);
  }
  __syncthreads();
  // --- stage 2: publish slice counts into histsum ---
  for (int i = tid; i < 4096; i += 512){
    int v = lh[i];
    if (v) atomicAdd(&histsum[g*4096 + i], v);
  }
  __threadfence();
  __syncthreads();
  if (tid == 0) atomicExch(&Dmark[(g << 4) + sl], MAGIC);
  // --- stage 3: wait for all 16 slices ---
  if (tid == 0){
    for (int s = 0; s < 16; s++)
      while (atomicAdd(&Dmark[(g << 4) + s], 0u) != MAGIC) __builtin_amdgcn_s_sleep(16);
  }
  __syncthreads();

  // --- stage 4: pick k-th bin (8 bins/thread, atomic loads of settled histsum) ---
  int h[8];
  {
    int* hb = histsum + g*4096 + 8*tid;
    #pragma unroll
    for (int q = 0; q < 8; q++) h[q] = (int)atomicAdd((u32*)&hb[q], 0u);
  }
  int part = 0;
  #pragma unroll
  for (int q = 0; q < 8; q++) part += h[q];
  int x = part;
  for (int d = 1; d < 64; d <<= 1){ int y = __shfl_up(x, d); if (lane >= d) x += y; }
  if (lane == 63) wsum[wid] = x;
  if (tid == 0){ lc = 0; lc2 = 0; }
  __syncthreads();
  int add = 0;
  for (int w = 0; w < wid; w++) add += wsum[w];
  int incl = x + add, excl = incl - part;
  if (excl < k && k <= incl){
    int cum = excl;
    #pragma unroll
    for (int q = 0; q < 8; q++){
      if (cum + h[q] >= k){
        sh_bs = 8*tid + q; sh_rem = k - cum;
        if (sl == 0){ bstarG[g] = 8*tid + q; remG[g] = k - cum; }
        break;
      }
      cum += h[q];
    }
  }
  __syncthreads();
  int bs = sh_bs;

  // --- stage 5: collect slice into LDS lists (arena reused), then to global ---
  u64* lmain = (u64*)arena;
  u64* lbuf2 = (u64*)(arena + 8192);
  __syncthreads();
  #pragma unroll 4
  for (int e = lo + tid; e < hiS; e += 512){
    u32 mu = mono_(__float_as_uint(p[e]));
    u64 key56 = (((u64)(~mu)) << 24) | (u32)(s0 + e);
    int bin = (int)(key56 >> 44);
    if (bin < bs){ int pos = atomicAdd(&lc, 1); lmain[pos] = key56; }        // global bound k-rem <= 999
    else if (bin == bs){ int pos = atomicAdd(&lc2, 1); if (pos < 1024) lbuf2[pos] = key56; }
  }
  __syncthreads();
  if (tid == 0){ gbase = atomicAdd(&cntg[g], lc); gbase2 = atomicAdd(&cnt2[g], lc2); }
  __syncthreads();
  int b1 = gbase, c1 = lc;
  for (int i = tid; i < c1; i += 512) mainG[g*1024 + b1 + i] = lmain[i];
  int b2 = gbase2, c2l = lc2 < 1024 ? lc2 : 1024;
  for (int i = tid; i < c2l; i += 512){
    int gp = b2 + i;
    if (gp < LCAP) LbufG[g*LCAP + gp] = lbuf2[i];
  }
}

// ---------- 2. tie-resolve + sort + decode + prep (r3-verbatim) ----------
__global__ __launch_bounds__(1024) void k_seldecode(const float* __restrict__ obj,
                                                    const float4* __restrict__ deltas,
                                                    const float4* __restrict__ anchors,
                                                    const u64* __restrict__ mainG,
                                                    const u64* __restrict__ LbufG,
                                                    const int* __restrict__ cntg,
                                                    const int* __restrict__ cnt2,
                                                    const int* __restrict__ remG,
                                                    const int* __restrict__ bstarG,
                                                    float4* boxL, float* scoreL,
                                                    float4* nbox, u64* okeyN, int* ncnt){
  int g = blockIdx.x, img = g/5, lvl = g%5;
  int s0 = lvl_off(lvl), n = lvl_len(lvl), k = lvl_k(lvl);
  const float* p = obj + img*R_TOT + s0;
  __shared__ u64 Lbuf[LCAP];
  __shared__ u64 mainL[1024];
  __shared__ float4 lbox[1024];
  __shared__ u64 lokey[1024];
  __shared__ unsigned char lval[1024];
  __shared__ int h16[16];
  __shared__ int sh_sc, sh_rem;
  __shared__ u64 sh_thr;
  int tid = threadIdx.x, lane = tid & 63;
  int nb = cntg[g];
  int c2 = cnt2[g];
  int rem = remG[g];
  int bs = bstarG[g];
  mainL[tid] = (tid < nb) ? mainG[g*1024 + tid] : ~0ull;
  if (tid == 0){ sh_sc = 0; sh_rem = rem; }
  int c2c = c2 < LCAP ? c2 : LCAP;
  for (int e = tid; e < c2c; e += 1024) Lbuf[e] = LbufG[g*LCAP + e];
  __syncthreads();
  if (c2 <= LCAP){
    for (int e = tid; e < c2; e += 1024){
      u64 kk = Lbuf[e];
      int rk = 0;
      for (int q = 0; q < c2; q++) rk += (Lbuf[q] < kk) ? 1 : 0;
      if (rk < rem){ int p2 = atomicAdd(&sh_sc, 1); mainL[nb + p2] = kk; }
    }
  } else {
    // fallback: 4-bit radix refine over global (never hit on bench data)
    if (tid == 0) sh_thr = ((u64)bs) << 44;
    __syncthreads();
    for (int shift = 40; shift >= 0; shift -= 4){
      if (tid < 16) h16[tid] = 0;
      __syncthreads();
      u64 pref = sh_thr;
      u64 himask = ~((1ull << (shift+4)) - 1ull);
      for (int e = tid; e < n; e += 1024){
        u32 mu = mono_(__float_as_uint(p[e]));
        u64 kk = (((u64)(~mu)) << 24) | (u32)(s0 + e);
        if ((kk & himask) == (pref & himask)) atomicAdd(&h16[(int)((kk >> shift) & 15)], 1);
      }
      __syncthreads();
      if (tid == 0){
        int r2 = sh_rem, cum = 0;
        for (int d = 0; d < 16; d++){
          int hb = h16[d];
          if (cum + hb >= r2){ sh_thr = pref | ((u64)d << shift); sh_rem = r2 - cum; break; }
          cum += hb;
        }
      }
      __syncthreads();
    }
    u64 thr = sh_thr;
    for (int e = tid; e < n; e += 1024){
      u32 mu = mono_(__float_as_uint(p[e]));
      u64 kk = (((u64)(~mu)) << 24) | (u32)(s0 + e);
      if ((int)(kk >> 44) == bs && kk <= thr){ int p2 = atomicAdd(&sh_sc, 1); mainL[nb + p2] = kk; }
    }
  }
  __syncthreads();
  for (int k2 = 2; k2 <= 1024; k2 <<= 1){
    for (int j = k2 >> 1; j > 0; j >>= 1){
      __syncthreads();
      int i = tid, ixj = i ^ j;
      if (ixj > i){
        u64 a = mainL[i], b = mainL[ixj];
        bool up = (i & k2) == 0;
        if ((a > b) == up){ mainL[i] = b; mainL[ixj] = a; }
      }
    }
  }
  __syncthreads();
  int r = tid, t = g*1024 + r;
  if (r < k){
    int idx = (int)(mainL[r] & 0xFFFFFFu);
    float4 a = anchors[idx];
    float4 d = deltas[img*R_TOT + idx];
    float o = obj[img*R_TOT + idx];
    float wa = fsub_(a.z, a.x), ha = fsub_(a.w, a.y);
    float cxa = fadd_(a.x, fmul_(0.5f, wa)), cya = fadd_(a.y, fmul_(0.5f, ha));
    float dw = fminf(d.z, BBOX_CLIP), dh = fminf(d.w, BBOX_CLIP);
    float cx = fadd_(fmul_(d.x, wa), cxa), cy = fadd_(fmul_(d.y, ha), cya);
    float w  = fmul_(expf(dw), wa),        h  = fmul_(expf(dh), ha);
    float x1 = fsub_(cx, fmul_(0.5f, w)), y1 = fsub_(cy, fmul_(0.5f, h));
    float x2 = fadd_(cx, fmul_(0.5f, w)), y2 = fadd_(cy, fmul_(0.5f, h));
    x1 = fminf(fmaxf(x1, 0.0f), IMG_SZ); y1 = fminf(fmaxf(y1, 0.0f), IMG_SZ);
    x2 = fminf(fmaxf(x2, 0.0f), IMG_SZ); y2 = fminf(fmaxf(y2, 0.0f), IMG_SZ);
    bool valid = (fsub_(x2, x1) >= 1e-3f) && (fsub_(y2, y1) >= 1e-3f);
    float e = expf(-o);
    float sig = __fdiv_rn(1.0f, fadd_(1.0f, e));
    float s = valid ? sig : -1.0f;
    u32 sb = __float_as_uint(s);
    u32 ms = (sb & 0x80000000u) ? ~sb : (sb | 0x80000000u);
    float4 b4 = make_float4(x1, y1, x2, y2);
    boxL[t] = b4;
    scoreL[t] = sig;
    lokey[r] = (((u64)(~ms)) << 32) | (u32)(lvl*1000 + r);
    lbox[r] = b4;
    lval[r] = valid ? 1 : 0;
  } else {
    lval[r] = 0;
  }
  __syncthreads();
  if (tid < 64){
    int cnt = 0;
    float off = (float)lvl * 801.0f;
    for (int base = 0; base < k; base += 64){
      int r2 = base + lane;
      bool v = (r2 < k) && lval[r2];
      float4 b = lbox[r2 < k ? r2 : 0];
      u64 mask = __ballot(v);
      int before = __popcll(mask & ((1ull << lane) - 1ull));
      if (v){
        int pos = cnt + before;
        nbox[g*1024 + pos] = make_float4(fadd_(b.x,off), fadd_(b.y,off), fadd_(b.z,off), fadd_(b.w,off));
        okeyN[g*1024 + pos] = lokey[r2];
      }
      cnt += __popcll(mask);
    }
    if (lane == 0) ncnt[g] = cnt;
  }
}

// ---------- 3. IoU bitmask (wide): row-major LTG2[row*16+q], diag slot 15;
//             areaB hoisted into LDS (bit-identical arithmetic) ----------
__global__ __launch_bounds__(64) void k_mask(const float4* __restrict__ nbox,
                                             const int* __restrict__ ncnt,
                                             u64* LTG2){
  int g = blockIdx.x, tr = blockIdx.y, tw = blockIdx.z;
  if (tw > tr) return;
  int m = ncnt[g];
  if (tr*64 >= m) return;
  __shared__ float4 shb[64];
  __shared__ float sharea[64];
  int lane = threadIdx.x;
  if (tw*64 + lane < m){
    float4 b = nbox[g*1024 + tw*64 + lane];
    shb[lane] = b;
    sharea[lane] = fmul_(fsub_(b.z,b.x), fsub_(b.w,b.y));
  }
  __syncthreads();
  int j = tr*64 + lane;
  if (j >= m) return;
  float4 a = nbox[g*1024 + j];
  float areaA = fmul_(fsub_(a.z,a.x), fsub_(a.w,a.y));
  int imax = m - tw*64; if (imax > 64) imax = 64;
  if (tw == tr){
    u64 bitsF = 0;
    for (int ii = lane+1; ii < imax; ii++){
      float4 b = shb[ii];
      float ltx = fmaxf(a.x, b.x), lty = fmaxf(a.y, b.y);
      float rbx = fminf(a.z, b.z), rby = fminf(a.w, b.w);
      float wx = fmaxf(fsub_(rbx, ltx), 0.0f), wy = fmaxf(fsub_(rby, lty), 0.0f);
      float inter = fmul_(wx, wy);
      float den = fadd_(fsub_(fadd_(areaA, sharea[ii]), inter), 1e-9f);
      if (__fdiv_rn(inter, den) > NMS_TH) bitsF |= (1ull << ii);
    }
    LTG2[((size_t)(g*1024 + j))*16 + 15] = bitsF;
  } else {
    u64 bits = 0;
    for (int ii = 0; ii < imax; ii++){
      float4 b = shb[ii];
      float ltx = fmaxf(a.x, b.x), lty = fmaxf(a.y, b.y);
      float rbx = fminf(a.z, b.z), rby = fminf(a.w, b.w);
      float wx = fmaxf(fsub_(rbx, ltx), 0.0f), wy = fmaxf(fsub_(rby, lty), 0.0f);
      float inter = fmul_(wx, wy);
      float den = fadd_(fsub_(fadd_(areaA, sharea[ii]), inter), 1e-9f);
      if (__fdiv_rn(inter, den) > NMS_TH) bits |= (1ull << ii);
    }
    LTG2[((size_t)(g*1024 + j))*16 + tw] = bits;
  }
}

struct ChunkBuf {
  ulonglong2 v0, v1, v2, v3, v4, v5, v6, v7;   // 16 u64: words 0..14 + diagF (slot 15)
  u64 ok;
};

__device__ __forceinline__ void issue_chunk(const u64* __restrict__ LT2,
                                            const u64* __restrict__ oK,
                                            int c, int lane, ChunkBuf& b){
  int row = c*64 + lane;
  const ulonglong2* rp = (const ulonglong2*)(LT2 + (size_t)row*16);
  b.v0 = rp[0]; b.v1 = rp[1]; b.v2 = rp[2]; b.v3 = rp[3];
  b.v4 = rp[4]; b.v5 = rp[5]; b.v6 = rp[6]; b.v7 = rp[7];
  b.ok = oK[row];
}

__device__ __forceinline__ void consume_chunk(const ChunkBuf& b, int c, int m, int lane,
                                              u64* KwR, u64* runsL, int& cnt){
  int row = c*64 + lane;
  bool inr = row < m;
  u64 supp = 0;
  #define TERM(q, val) supp |= (((q) < c) ? (val) : 0ull) & KwR[q];
  TERM(0,  b.v0.x) TERM(1,  b.v0.y) TERM(2,  b.v1.x) TERM(3,  b.v1.y)
  TERM(4,  b.v2.x) TERM(5,  b.v2.y) TERM(6,  b.v3.x) TERM(7,  b.v3.y)
  TERM(8,  b.v4.x) TERM(9,  b.v4.y) TERM(10, b.v5.x) TERM(11, b.v5.y)
  TERM(12, b.v6.x) TERM(13, b.v6.y) TERM(14, b.v7.x)
  #undef TERM
  u64 fwd = inr ? b.v7.y : 0;
  u64 live = __ballot(inr && (supp == 0));
  u64 fz = __ballot(fwd != 0);
  u64 kept = 0;
  while (1){
    u64 lf = live & fz;
    if (!lf){ kept |= live; break; }       // remaining live lanes suppress nobody
    int i = __builtin_ctzll(lf);
    u64 bi = 1ull << i;
    u64 below = live & (bi - 1ull);        // live lanes before i: fwd==0, batch-keep
    kept |= below | bi;
    live &= ~(below | bi);
    live &= ~readlane64(fwd, i);
  }
  KwR[c] = kept;                            // uniform; in-wave DS ordering suffices
  bool kp = (kept >> lane) & 1ull;
  int before = __popcll(kept & ((1ull << lane) - 1ull));
  if (kp) runsL[cnt + before] = b.ok;
  cnt += __popcll(kept);
}

// ---------- 4. fused greedy scan + merge (r3-verbatim) ----------
__global__ __launch_bounds__(1024) void k_scanmerge(const u64* __restrict__ LTG2,
                                                    const int* __restrict__ ncnt,
                                                    const u64* __restrict__ okeyN,
                                                    const float4* __restrict__ boxL,
                                                    const float* __restrict__ scoreL,
                                                    float* out){
  int img = blockIdx.x, tid = threadIdx.x, lane = tid & 63, wid = tid >> 6;
  __shared__ u64 runs[5*1024];
  __shared__ u64 Kw[5][16];
  __shared__ int cl[5];
  if (wid < 5){
    int l = wid, g = img*5 + l;
    int m = ncnt[g];
    int nch = (m + 63) >> 6;
    const u64* LT2 = LTG2 + ((size_t)g*1024)*16;
    const u64* oK = okeyN + g*1024;
    u64* KwR = &Kw[l][0];
    u64* runsL = &runs[l*1024];
    int cnt = 0;
    ChunkBuf A, B;
    if (nch > 0){
      issue_chunk(LT2, oK, 0, lane, A);
      int c = 0;
      while (c < nch){
        if (c+1 < nch) issue_chunk(LT2, oK, c+1, lane, B);
        consume_chunk(A, c, m, lane, KwR, runsL, cnt);
        c++;
        if (c >= nch) break;
        if (c+1 < nch) issue_chunk(LT2, oK, c+1, lane, A);
        consume_chunk(B, c, m, lane, KwR, runsL, cnt);
        c++;
      }
    }
    if (lane == 0) cl[l] = cnt;
  } else {
    for (int t = tid - 320; t < POST; t += 704){
      out[img*POST*4 + t*4 + 0] = 0.0f;
      out[img*POST*4 + t*4 + 1] = 0.0f;
      out[img*POST*4 + t*4 + 2] = 0.0f;
      out[img*POST*4 + t*4 + 3] = 0.0f;
      out[2*POST*4 + img*POST + t] = -1.0f;
    }
  }
  __syncthreads();
  for (int idx = tid; idx < 5*1024; idx += 1024){
    int l = idx >> 10, i = idx & 1023;
    if (i < cl[l]){
      u64 key = runs[l*1024 + i];
      int o0 = l+1; if (o0 >= 5) o0 -= 5;
      int o1 = l+2; if (o1 >= 5) o1 -= 5;
      int o2 = l+3; if (o2 >= 5) o2 -= 5;
      int o3 = l+4; if (o3 >= 5) o3 -= 5;
      const u64* r0 = runs + (o0 << 10);
      const u64* r1 = runs + (o1 << 10);
      const u64* r2 = runs + (o2 << 10);
      const u64* r3 = runs + (o3 << 10);
      int lo0 = 0, hi0 = cl[o0];
      int lo1 = 0, hi1 = cl[o1];
      int lo2 = 0, hi2 = cl[o2];
      int lo3 = 0, hi3 = cl[o3];
      #pragma unroll 1
      for (int st = 0; st < 11; st++){
        int m0 = (lo0+hi0)>>1, m1 = (lo1+hi1)>>1, m2 = (lo2+hi2)>>1, m3 = (lo3+hi3)>>1;
        u64 a0 = r0[m0], a1 = r1[m1], a2 = r2[m2], a3 = r3[m3];
        if (lo0 < hi0){ if (a0 < key) lo0 = m0+1; else hi0 = m0; }
        if (lo1 < hi1){ if (a1 < key) lo1 = m1+1; else hi1 = m1; }
        if (lo2 < hi2){ if (a2 < key) lo2 = m2+1; else hi2 = m2; }
        if (lo3 < hi3){ if (a3 < key) lo3 = m3+1; else hi3 = m3; }
      }
      int rank = i + lo0 + lo1 + lo2 + lo3;
      if (rank < POST){
        int pos = (int)(key & 0xFFFFFFFFull);
        int lvl = pos / 1000, r = pos - lvl*1000;
        int gg = img*5 + lvl;
        float4 bo = boxL[gg*1024 + r];
        float sc = scoreL[gg*1024 + r];
        out[img*POST*4 + rank*4 + 0] = bo.x;
        out[img*POST*4 + rank*4 + 1] = bo.y;
        out[img*POST*4 + rank*4 + 2] = bo.z;
        out[img*POST*4 + rank*4 + 3] = bo.w;
        out[2*POST*4 + img*POST + rank] = sc;
      }
    }
  }
}

extern "C" void kernel_launch(void* const* d_in, const int* in_sizes, int n_in,
                              void* d_out, int out_size, void* d_ws, size_t ws_size,
                              hipStream_t stream){
  (void)in_sizes; (void)n_in; (void)out_size; (void)ws_size;
  const float*  obj     = (const float*)d_in[0];
  const float4* deltas  = (const float4*)d_in[1];
  const float4* anchors = (const float4*)d_in[2];
  float* out = (float*)d_out;
  char* ws = (char*)d_ws;
  int* histsum = (int*)(ws + 0);           // 10*4096 int    -> 163840
  u32* Zmark   = (u32*)(ws + 163840);      // 10 u32         -> 163880 (pad 163904)
  u32* Dmark   = (u32*)(ws + 163904);      // 160 u32        -> 164544
  int* bstarG  = (int*)(ws + 164544);      // 10             -> 164584 (pad 164608)
  int* remG    = (int*)(ws + 164608);      //                -> 164648 (pad 164672)
  int* cntg    = (int*)(ws + 164672);      //                -> 164712 (pad 164736)
  int* cnt2    = (int*)(ws + 164736);      //                -> 164776 (pad 164800)
  u64* mainG   = (u64*)(ws + 164800);      // 10*1024 u64    -> 246720
  u64* LbufG   = (u64*)(ws + 246720);      // 10*1024 u64    -> 328640
  float4* boxL = (float4*)(ws + 328640);   // 10*1024 f4     -> 492480
  float* scoreL= (float*)(ws + 492480);    // 10*1024 f32    -> 533440
  u64* okeyN   = (u64*)(ws + 533440);      // 10*1024 u64    -> 615360
  float4* nbox = (float4*)(ws + 615360);   // 10*1024 f4     -> 779200
  u64* LTG2    = (u64*)(ws + 779200);      // 10*1024*16 u64 -> 2089920
  int* ncnt    = (int*)(ws + 2089920);     // 10 int

  {
    dim3 gh(10, 16);
    k_histcollect<<<gh, 512, 0, stream>>>(obj, histsum, Zmark, Dmark,
                                          bstarG, remG, cntg, cnt2, mainG, LbufG);
  }
  k_seldecode<<<10, 1024, 0, stream>>>(obj, deltas, anchors, mainG, LbufG, cntg, cnt2,
                                       remG, bstarG, boxL, scoreL, nbox, okeyN, ncnt);
  {
    dim3 gm(10, 16, 16);
    k_mask<<<gm, 64, 0, stream>>>(nbox, ncnt, LTG2);
  }
  k_scanmerge<<<2, 1024, 0, stream>>>(LTG2, ncnt, okeyN, boxL, scoreL, out);
}

// Round 10
// 150.833 us; speedup vs baseline: 1.8241x; 1.1258x over previous
//
#include <hip/hip_runtime.h>

typedef unsigned long long u64;
typedef unsigned int u32;

#define R_TOT 159882
#define POST 1000
#define IMG_SZ 800.0f
#define NMS_TH 0.7f
#define BBOX_CLIP 4.135166556742356f
#define LCAP 1024

__device__ __forceinline__ float fadd_(float a, float b){ return __fadd_rn(a,b); }
__device__ __forceinline__ float fsub_(float a, float b){ return __fsub_rn(a,b); }
__device__ __forceinline__ float fmul_(float a, float b){ return __fmul_rn(a,b); }

__device__ __forceinline__ int lvl_len(int l){ const int L[5]={120000,30000,7500,1875,507}; return L[l]; }
__device__ __forceinline__ int lvl_off(int l){ const int L[5]={0,120000,150000,157500,159375}; return L[l]; }
__device__ __forceinline__ int lvl_k(int l){ const int L[5]={1000,1000,1000,1000,507}; return L[l]; }

__device__ __forceinline__ u32 mono_(u32 u){ return (u & 0x80000000u) ? ~u : (u | 0x80000000u); }

__device__ __forceinline__ u64 readlane64(u64 v, int i){
  u32 lo = (u32)__builtin_amdgcn_readlane((int)(u32)v, i);
  u32 hi = (u32)__builtin_amdgcn_readlane((int)(u32)(v >> 32), i);
  return ((u64)hi << 32) | (u64)lo;
}

// ---------- 1. hist+pick+collect, NO cross-block dependency:
//    each block histograms its WHOLE level (L2-hot, 16x redundant but tiny),
//    picks b*/rem in-block, collects its own slice into fixed per-slice regions
//    (plain stores + per-slice counts; no global atomics, no zero-init). ----------
__global__ __launch_bounds__(512) void k_histcollect(const float* __restrict__ obj,
                                                     u64* mainS, u64* tieS,
                                                     int* cntS, int* cnt2S,
                                                     int* bstarG, int* remG){
  int g = blockIdx.x, sl = blockIdx.y;
  int img = g/5, lvl = g%5;
  int n = lvl_len(lvl), s0 = lvl_off(lvl), k = lvl_k(lvl);
  int tid = threadIdx.x, lane = tid & 63, wid = tid >> 6;
  __shared__ __align__(16) char arena[16384];   // lh[4096] ints, then lmain/lbuf2
  __shared__ int wsum[8];
  __shared__ int sh_bs, sh_rem, lc, lc2;
  int* lh = (int*)arena;
  for (int i = tid; i < 4096; i += 512) lh[i] = 0;
  __syncthreads();
  const float* p = obj + img*R_TOT + s0;

  // --- phase A: full-level histogram, 8-deep guard-free batched loads ---
  {
    int full = n >> 12;               // iterations of 4096 elems
    for (int it = 0; it < full; it++){
      int e0 = (it << 12) + tid;
      float v[8];
      #pragma unroll
      for (int q = 0; q < 8; q++) v[q] = p[e0 + (q << 9)];
      #pragma unroll
      for (int q = 0; q < 8; q++){
        u32 mu = mono_(__float_as_uint(v[q]));
        atomicAdd(&lh[(~mu) >> 20], 1);
      }
    }
    int e0 = (full << 12) + tid;
    float v[8];
    #pragma unroll
    for (int q = 0; q < 8; q++){ int e = e0 + (q << 9); v[q] = (e < n) ? p[e] : 0.0f; }
    #pragma unroll
    for (int q = 0; q < 8; q++){
      int e = e0 + (q << 9);
      if (e < n){
        u32 mu = mono_(__float_as_uint(v[q]));
        atomicAdd(&lh[(~mu) >> 20], 1);
      }
    }
  }
  __syncthreads();

  // --- phase B: pick k-th bin (8 bins/thread, 8-wave prefix scan) ---
  int h[8];
  #pragma unroll
  for (int q = 0; q < 8; q++) h[q] = lh[8*tid + q];
  int part = 0;
  #pragma unroll
  for (int q = 0; q < 8; q++) part += h[q];
  int x = part;
  for (int d = 1; d < 64; d <<= 1){ int y = __shfl_up(x, d); if (lane >= d) x += y; }
  if (lane == 63) wsum[wid] = x;
  __syncthreads();
  int add = 0;
  for (int w = 0; w < wid; w++) add += wsum[w];
  int incl = x + add, excl = incl - part;
  if (excl < k && k <= incl){
    int cum = excl;
    #pragma unroll
    for (int q = 0; q < 8; q++){
      if (cum + h[q] >= k){
        sh_bs = 8*tid + q; sh_rem = k - cum;
        if (sl == 0){ bstarG[g] = 8*tid + q; remG[g] = k - cum; }
        break;
      }
      cum += h[q];
    }
  }
  __syncthreads();
  int bs = sh_bs;

  // --- phase C: collect own slice into LDS lists (arena reused), 8-deep batched ---
  u64* lmain = (u64*)arena;
  u64* lbuf2 = (u64*)(arena + 8192);
  if (tid == 0){ lc = 0; lc2 = 0; }
  __syncthreads();
  int lo = (int)((long long)n * sl / 16), hiS = (int)((long long)n * (sl+1) / 16);
  int len = hiS - lo;
  {
    int full = len >> 12;
    for (int it = 0; it < full; it++){
      int e0 = lo + (it << 12) + tid;
      float v[8];
      #pragma unroll
      for (int q = 0; q < 8; q++) v[q] = p[e0 + (q << 9)];
      #pragma unroll
      for (int q = 0; q < 8; q++){
        int e = e0 + (q << 9);
        u32 mu = mono_(__float_as_uint(v[q]));
        u64 key56 = (((u64)(~mu)) << 24) | (u32)(s0 + e);
        int bin = (int)(key56 >> 44);
        if (bin < bs){ int pos = atomicAdd(&lc, 1); lmain[pos] = key56; }      // slice cnt <= global 999
        else if (bin == bs){ int pos = atomicAdd(&lc2, 1); if (pos < 1024) lbuf2[pos] = key56; }
      }
    }
    int e0 = lo + (full << 12) + tid;
    float v[8];
    #pragma unroll
    for (int q = 0; q < 8; q++){ int e = e0 + (q << 9); v[q] = (e < hiS) ? p[e] : 0.0f; }
    #pragma unroll
    for (int q = 0; q < 8; q++){
      int e = e0 + (q << 9);
      if (e < hiS){
        u32 mu = mono_(__float_as_uint(v[q]));
        u64 key56 = (((u64)(~mu)) << 24) | (u32)(s0 + e);
        int bin = (int)(key56 >> 44);
        if (bin < bs){ int pos = atomicAdd(&lc, 1); lmain[pos] = key56; }
        else if (bin == bs){ int pos = atomicAdd(&lc2, 1); if (pos < 1024) lbuf2[pos] = key56; }
      }
    }
  }
  __syncthreads();
  int idx16 = g*16 + sl;
  if (tid == 0){ cntS[idx16] = lc; cnt2S[idx16] = lc2; }   // true counts (lc2 may exceed 1024 -> fallback)
  for (int i = tid; i < lc; i += 512) mainS[idx16*1024 + i] = lmain[i];
  int c2l = lc2 < 1024 ? lc2 : 1024;
  for (int i = tid; i < c2l; i += 512) tieS[idx16*1024 + i] = lbuf2[i];
}

// ---------- 2. tie-resolve + sort + decode + prep (r3 body; per-slice concat load) ----------
__global__ __launch_bounds__(1024) void k_seldecode(const float* __restrict__ obj,
                                                    const float4* __restrict__ deltas,
                                                    const float4* __restrict__ anchors,
                                                    const u64* __restrict__ mainS,
                                                    const u64* __restrict__ tieS,
                                                    const int* __restrict__ cntS,
                                                    const int* __restrict__ cnt2S,
                                                    const int* __restrict__ remG,
                                                    const int* __restrict__ bstarG,
                                                    float4* boxL, float* scoreL,
                                                    float4* nbox, u64* okeyN, int* ncnt){
  int g = blockIdx.x, img = g/5, lvl = g%5;
  int s0 = lvl_off(lvl), n = lvl_len(lvl), k = lvl_k(lvl);
  const float* p = obj + img*R_TOT + s0;
  __shared__ u64 Lbuf[LCAP];
  __shared__ u64 mainL[1024];
  __shared__ float4 lbox[1024];
  __shared__ u64 lokey[1024];
  __shared__ unsigned char lval[1024];
  __shared__ int h16[16];
  __shared__ int scnt[16], tcnt[16];
  __shared__ int sbase[17], tbase[17];
  __shared__ int sh_sc, sh_rem;
  __shared__ u64 sh_thr;
  int tid = threadIdx.x, lane = tid & 63;
  if (tid < 16){ scnt[tid] = cntS[g*16 + tid]; tcnt[tid] = cnt2S[g*16 + tid]; }
  __syncthreads();
  if (tid == 0){
    int s = 0, t2 = 0;
    #pragma unroll
    for (int q = 0; q < 16; q++){ sbase[q] = s; s += scnt[q]; tbase[q] = t2; t2 += tcnt[q]; }
    sbase[16] = s; tbase[16] = t2;
  }
  __syncthreads();
  int nb = sbase[16];
  int c2 = tbase[16];
  int rem = remG[g];
  int bs = bstarG[g];
  // concat main sublists
  {
    u64 vmain = ~0ull;
    if (tid < nb){
      int sl = 0;
      #pragma unroll
      for (int q = 1; q < 16; q++) sl += (tid >= sbase[q]) ? 1 : 0;
      vmain = mainS[(g*16 + sl)*1024 + (tid - sbase[sl])];
    }
    mainL[tid] = vmain;
  }
  if (tid == 0){ sh_sc = 0; sh_rem = rem; }
  int c2c = c2 < LCAP ? c2 : LCAP;
  for (int e = tid; e < c2c; e += 1024){
    int sl = 0;
    #pragma unroll
    for (int q = 1; q < 16; q++) sl += (e >= tbase[q]) ? 1 : 0;
    Lbuf[e] = tieS[(g*16 + sl)*1024 + (e - tbase[sl])];
  }
  __syncthreads();
  if (c2 <= LCAP){
    for (int e = tid; e < c2; e += 1024){
      u64 kk = Lbuf[e];
      int rk = 0;
      for (int q = 0; q < c2; q++) rk += (Lbuf[q] < kk) ? 1 : 0;
      if (rk < rem){ int p2 = atomicAdd(&sh_sc, 1); mainL[nb + p2] = kk; }
    }
  } else {
    // fallback: 4-bit radix refine over global (never hit on bench data)
    if (tid == 0) sh_thr = ((u64)bs) << 44;
    __syncthreads();
    for (int shift = 40; shift >= 0; shift -= 4){
      if (tid < 16) h16[tid] = 0;
      __syncthreads();
      u64 pref = sh_thr;
      u64 himask = ~((1ull << (shift+4)) - 1ull);
      for (int e = tid; e < n; e += 1024){
        u32 mu = mono_(__float_as_uint(p[e]));
        u64 kk = (((u64)(~mu)) << 24) | (u32)(s0 + e);
        if ((kk & himask) == (pref & himask)) atomicAdd(&h16[(int)((kk >> shift) & 15)], 1);
      }
      __syncthreads();
      if (tid == 0){
        int r2 = sh_rem, cum = 0;
        for (int d = 0; d < 16; d++){
          int hb = h16[d];
          if (cum + hb >= r2){ sh_thr = pref | ((u64)d << shift); sh_rem = r2 - cum; break; }
          cum += hb;
        }
      }
      __syncthreads();
    }
    u64 thr = sh_thr;
    for (int e = tid; e < n; e += 1024){
      u32 mu = mono_(__float_as_uint(p[e]));
      u64 kk = (((u64)(~mu)) << 24) | (u32)(s0 + e);
      if ((int)(kk >> 44) == bs && kk <= thr){ int p2 = atomicAdd(&sh_sc, 1); mainL[nb + p2] = kk; }
    }
  }
  __syncthreads();
  // --- bitonic sort 1024 ---
  for (int k2 = 2; k2 <= 1024; k2 <<= 1){
    for (int j = k2 >> 1; j > 0; j >>= 1){
      __syncthreads();
      int i = tid, ixj = i ^ j;
      if (ixj > i){
        u64 a = mainL[i], b = mainL[ixj];
        bool up = (i & k2) == 0;
        if ((a > b) == up){ mainL[i] = b; mainL[ixj] = a; }
      }
    }
  }
  __syncthreads();
  // --- decode + clip + valid + sigmoid + okey ---
  int r = tid, t = g*1024 + r;
  if (r < k){
    int idx = (int)(mainL[r] & 0xFFFFFFu);
    float4 a = anchors[idx];
    float4 d = deltas[img*R_TOT + idx];
    float o = obj[img*R_TOT + idx];
    float wa = fsub_(a.z, a.x), ha = fsub_(a.w, a.y);
    float cxa = fadd_(a.x, fmul_(0.5f, wa)), cya = fadd_(a.y, fmul_(0.5f, ha));
    float dw = fminf(d.z, BBOX_CLIP), dh = fminf(d.w, BBOX_CLIP);
    float cx = fadd_(fmul_(d.x, wa), cxa), cy = fadd_(fmul_(d.y, ha), cya);
    float w  = fmul_(expf(dw), wa),        h  = fmul_(expf(dh), ha);
    float x1 = fsub_(cx, fmul_(0.5f, w)), y1 = fsub_(cy, fmul_(0.5f, h));
    float x2 = fadd_(cx, fmul_(0.5f, w)), y2 = fadd_(cy, fmul_(0.5f, h));
    x1 = fminf(fmaxf(x1, 0.0f), IMG_SZ); y1 = fminf(fmaxf(y1, 0.0f), IMG_SZ);
    x2 = fminf(fmaxf(x2, 0.0f), IMG_SZ); y2 = fminf(fmaxf(y2, 0.0f), IMG_SZ);
    bool valid = (fsub_(x2, x1) >= 1e-3f) && (fsub_(y2, y1) >= 1e-3f);
    float e = expf(-o);
    float sig = __fdiv_rn(1.0f, fadd_(1.0f, e));
    float s = valid ? sig : -1.0f;
    u32 sb = __float_as_uint(s);
    u32 ms = (sb & 0x80000000u) ? ~sb : (sb | 0x80000000u);
    float4 b4 = make_float4(x1, y1, x2, y2);
    boxL[t] = b4;
    scoreL[t] = sig;
    lokey[r] = (((u64)(~ms)) << 32) | (u32)(lvl*1000 + r);
    lbox[r] = b4;
    lval[r] = valid ? 1 : 0;
  } else {
    lval[r] = 0;
  }
  __syncthreads();
  if (tid < 64){
    int cnt = 0;
    float off = (float)lvl * 801.0f;
    for (int base = 0; base < k; base += 64){
      int r2 = base + lane;
      bool v = (r2 < k) && lval[r2];
      float4 b = lbox[r2 < k ? r2 : 0];
      u64 mask = __ballot(v);
      int before = __popcll(mask & ((1ull << lane) - 1ull));
      if (v){
        int pos = cnt + before;
        nbox[g*1024 + pos] = make_float4(fadd_(b.x,off), fadd_(b.y,off), fadd_(b.z,off), fadd_(b.w,off));
        okeyN[g*1024 + pos] = lokey[r2];
      }
      cnt += __popcll(mask);
    }
    if (lane == 0) ncnt[g] = cnt;
  }
}

// ---------- 3. IoU bitmask (wide): row-major LTG2[row*16+q], diag slot 15 ----------
__global__ __launch_bounds__(64) void k_mask(const float4* __restrict__ nbox,
                                             const int* __restrict__ ncnt,
                                             u64* LTG2){
  int g = blockIdx.x, tr = blockIdx.y, tw = blockIdx.z;
  if (tw > tr) return;
  int m = ncnt[g];
  if (tr*64 >= m) return;
  __shared__ float4 shb[64];
  __shared__ float sharea[64];
  int lane = threadIdx.x;
  if (tw*64 + lane < m){
    float4 b = nbox[g*1024 + tw*64 + lane];
    shb[lane] = b;
    sharea[lane] = fmul_(fsub_(b.z,b.x), fsub_(b.w,b.y));
  }
  __syncthreads();
  int j = tr*64 + lane;
  if (j >= m) return;
  float4 a = nbox[g*1024 + j];
  float areaA = fmul_(fsub_(a.z,a.x), fsub_(a.w,a.y));
  int imax = m - tw*64; if (imax > 64) imax = 64;
  if (tw == tr){
    u64 bitsF = 0;
    for (int ii = lane+1; ii < imax; ii++){
      float4 b = shb[ii];
      float ltx = fmaxf(a.x, b.x), lty = fmaxf(a.y, b.y);
      float rbx = fminf(a.z, b.z), rby = fminf(a.w, b.w);
      float wx = fmaxf(fsub_(rbx, ltx), 0.0f), wy = fmaxf(fsub_(rby, lty), 0.0f);
      float inter = fmul_(wx, wy);
      float den = fadd_(fsub_(fadd_(areaA, sharea[ii]), inter), 1e-9f);
      if (__fdiv_rn(inter, den) > NMS_TH) bitsF |= (1ull << ii);
    }
    LTG2[((size_t)(g*1024 + j))*16 + 15] = bitsF;
  } else {
    u64 bits = 0;
    for (int ii = 0; ii < imax; ii++){
      float4 b = shb[ii];
      float ltx = fmaxf(a.x, b.x), lty = fmaxf(a.y, b.y);
      float rbx = fminf(a.z, b.z), rby = fminf(a.w, b.w);
      float wx = fmaxf(fsub_(rbx, ltx), 0.0f), wy = fmaxf(fsub_(rby, lty), 0.0f);
      float inter = fmul_(wx, wy);
      float den = fadd_(fsub_(fadd_(areaA, sharea[ii]), inter), 1e-9f);
      if (__fdiv_rn(inter, den) > NMS_TH) bits |= (1ull << ii);
    }
    LTG2[((size_t)(g*1024 + j))*16 + tw] = bits;
  }
}

struct ChunkBuf {
  ulonglong2 v0, v1, v2, v3, v4, v5, v6, v7;   // 16 u64: words 0..14 + diagF (slot 15)
  u64 ok;
};

__device__ __forceinline__ void issue_chunk(const u64* __restrict__ LT2,
                                            const u64* __restrict__ oK,
                                            int c, int lane, ChunkBuf& b){
  int row = c*64 + lane;
  const ulonglong2* rp = (const ulonglong2*)(LT2 + (size_t)row*16);
  b.v0 = rp[0]; b.v1 = rp[1]; b.v2 = rp[2]; b.v3 = rp[3];
  b.v4 = rp[4]; b.v5 = rp[5]; b.v6 = rp[6]; b.v7 = rp[7];
  b.ok = oK[row];
}

__device__ __forceinline__ void consume_chunk(const ChunkBuf& b, int c, int m, int lane,
                                              u64* KwR, u64* runsL, int& cnt){
  int row = c*64 + lane;
  bool inr = row < m;
  u64 supp = 0;
  #define TERM(q, val) supp |= (((q) < c) ? (val) : 0ull) & KwR[q];
  TERM(0,  b.v0.x) TERM(1,  b.v0.y) TERM(2,  b.v1.x) TERM(3,  b.v1.y)
  TERM(4,  b.v2.x) TERM(5,  b.v2.y) TERM(6,  b.v3.x) TERM(7,  b.v3.y)
  TERM(8,  b.v4.x) TERM(9,  b.v4.y) TERM(10, b.v5.x) TERM(11, b.v5.y)
  TERM(12, b.v6.x) TERM(13, b.v6.y) TERM(14, b.v7.x)
  #undef TERM
  u64 fwd = inr ? b.v7.y : 0;
  u64 live = __ballot(inr && (supp == 0));
  u64 fz = __ballot(fwd != 0);
  u64 kept = 0;
  while (1){
    u64 lf = live & fz;
    if (!lf){ kept |= live; break; }       // remaining live lanes suppress nobody
    int i = __builtin_ctzll(lf);
    u64 bi = 1ull << i;
    u64 below = live & (bi - 1ull);        // live lanes before i: fwd==0, batch-keep
    kept |= below | bi;
    live &= ~(below | bi);
    live &= ~readlane64(fwd, i);
  }
  KwR[c] = kept;                            // uniform; in-wave DS ordering suffices
  bool kp = (kept >> lane) & 1ull;
  int before = __popcll(kept & ((1ull << lane) - 1ull));
  if (kp) runsL[cnt + before] = b.ok;
  cnt += __popcll(kept);
}

// ---------- 4. fused greedy scan + merge (r3-verbatim) ----------
__global__ __launch_bounds__(1024) void k_scanmerge(const u64* __restrict__ LTG2,
                                                    const int* __restrict__ ncnt,
                                                    const u64* __restrict__ okeyN,
                                                    const float4* __restrict__ boxL,
                                                    const float* __restrict__ scoreL,
                                                    float* out){
  int img = blockIdx.x, tid = threadIdx.x, lane = tid & 63, wid = tid >> 6;
  __shared__ u64 runs[5*1024];
  __shared__ u64 Kw[5][16];
  __shared__ int cl[5];
  if (wid < 5){
    int l = wid, g = img*5 + l;
    int m = ncnt[g];
    int nch = (m + 63) >> 6;
    const u64* LT2 = LTG2 + ((size_t)g*1024)*16;
    const u64* oK = okeyN + g*1024;
    u64* KwR = &Kw[l][0];
    u64* runsL = &runs[l*1024];
    int cnt = 0;
    ChunkBuf A, B;
    if (nch > 0){
      issue_chunk(LT2, oK, 0, lane, A);
      int c = 0;
      while (c < nch){
        if (c+1 < nch) issue_chunk(LT2, oK, c+1, lane, B);
        consume_chunk(A, c, m, lane, KwR, runsL, cnt);
        c++;
        if (c >= nch) break;
        if (c+1 < nch) issue_chunk(LT2, oK, c+1, lane, A);
        consume_chunk(B, c, m, lane, KwR, runsL, cnt);
        c++;
      }
    }
    if (lane == 0) cl[l] = cnt;
  } else {
    for (int t = tid - 320; t < POST; t += 704){
      out[img*POST*4 + t*4 + 0] = 0.0f;
      out[img*POST*4 + t*4 + 1] = 0.0f;
      out[img*POST*4 + t*4 + 2] = 0.0f;
      out[img*POST*4 + t*4 + 3] = 0.0f;
      out[2*POST*4 + img*POST + t] = -1.0f;
    }
  }
  __syncthreads();
  for (int idx = tid; idx < 5*1024; idx += 1024){
    int l = idx >> 10, i = idx & 1023;
    if (i < cl[l]){
      u64 key = runs[l*1024 + i];
      int o0 = l+1; if (o0 >= 5) o0 -= 5;
      int o1 = l+2; if (o1 >= 5) o1 -= 5;
      int o2 = l+3; if (o2 >= 5) o2 -= 5;
      int o3 = l+4; if (o3 >= 5) o3 -= 5;
      const u64* r0 = runs + (o0 << 10);
      const u64* r1 = runs + (o1 << 10);
      const u64* r2 = runs + (o2 << 10);
      const u64* r3 = runs + (o3 << 10);
      int lo0 = 0, hi0 = cl[o0];
      int lo1 = 0, hi1 = cl[o1];
      int lo2 = 0, hi2 = cl[o2];
      int lo3 = 0, hi3 = cl[o3];
      #pragma unroll 1
      for (int st = 0; st < 11; st++){
        int m0 = (lo0+hi0)>>1, m1 = (lo1+hi1)>>1, m2 = (lo2+hi2)>>1, m3 = (lo3+hi3)>>1;
        u64 a0 = r0[m0], a1 = r1[m1], a2 = r2[m2], a3 = r3[m3];
        if (lo0 < hi0){ if (a0 < key) lo0 = m0+1; else hi0 = m0; }
        if (lo1 < hi1){ if (a1 < key) lo1 = m1+1; else hi1 = m1; }
        if (lo2 < hi2){ if (a2 < key) lo2 = m2+1; else hi2 = m2; }
        if (lo3 < hi3){ if (a3 < key) lo3 = m3+1; else hi3 = m3; }
      }
      int rank = i + lo0 + lo1 + lo2 + lo3;
      if (rank < POST){
        int pos = (int)(key & 0xFFFFFFFFull);
        int lvl = pos / 1000, r = pos - lvl*1000;
        int gg = img*5 + lvl;
        float4 bo = boxL[gg*1024 + r];
        float sc = scoreL[gg*1024 + r];
        out[img*POST*4 + rank*4 + 0] = bo.x;
        out[img*POST*4 + rank*4 + 1] = bo.y;
        out[img*POST*4 + rank*4 + 2] = bo.z;
        out[img*POST*4 + rank*4 + 3] = bo.w;
        out[2*POST*4 + img*POST + rank] = sc;
      }
    }
  }
}

extern "C" void kernel_launch(void* const* d_in, const int* in_sizes, int n_in,
                              void* d_out, int out_size, void* d_ws, size_t ws_size,
                              hipStream_t stream){
  (void)in_sizes; (void)n_in; (void)out_size; (void)ws_size;
  const float*  obj     = (const float*)d_in[0];
  const float4* deltas  = (const float4*)d_in[1];
  const float4* anchors = (const float4*)d_in[2];
  float* out = (float*)d_out;
  char* ws = (char*)d_ws;
  u64* mainS   = (u64*)(ws + 0);           // 160*1024 u64   -> 1310720
  u64* tieS    = (u64*)(ws + 1310720);     // 160*1024 u64   -> 2621440
  int* cntS    = (int*)(ws + 2621440);     // 160 int        -> 2622080
  int* cnt2S   = (int*)(ws + 2622080);     // 160 int        -> 2622720
  int* bstarG  = (int*)(ws + 2622720);     // 10 int         -> 2622784 (pad)
  int* remG    = (int*)(ws + 2622784);     // 10 int         -> 2622848 (pad)
  float4* boxL = (float4*)(ws + 2622848);  // 10*1024 f4     -> 2786688
  float* scoreL= (float*)(ws + 2786688);   // 10*1024 f32    -> 2827648
  u64* okeyN   = (u64*)(ws + 2827648);     // 10*1024 u64    -> 2909568
  float4* nbox = (float4*)(ws + 2909568);  // 10*1024 f4     -> 3073408
  u64* LTG2    = (u64*)(ws + 3073408);     // 10*1024*16 u64 -> 4384128
  int* ncnt    = (int*)(ws + 4384128);     // 10 int

  {
    dim3 gh(10, 16);
    k_histcollect<<<gh, 512, 0, stream>>>(obj, mainS, tieS, cntS, cnt2S, bstarG, remG);
  }
  k_seldecode<<<10, 1024, 0, stream>>>(obj, deltas, anchors, mainS, tieS, cntS, cnt2S,
                                       remG, bstarG, boxL, scoreL, nbox, okeyN, ncnt);
  {
    dim3 gm(10, 16, 16);
    k_mask<<<gm, 64, 0, stream>>>(nbox, ncnt, LTG2);
  }
  k_scanmerge<<<2, 1024, 0, stream>>>(LTG2, ncnt, okeyN, boxL, scoreL, out);
}